// Round 5
// baseline (3638.603 us; speedup 1.0000x reference)
//
#include <hip/hip_runtime.h>
#include <cstddef>

#define NN 50000
#define EE 1600000
#define IN_DIM 512
#define HID 256
#define OUT_DIM 40
#define KSTEPS 10
#define BN_EPS 1e-5f

#define HB 256                 // histogram/scatter blocks
#define ECHUNK (EE / HB)       // 6250 edges per block
#define BNODE 40               // dest nodes per bucket
#define NB 1280                // buckets (covers 51200 >= NN)
#define HRW ((NN + 3) / 4)     // 12500 words of packed byte counts

typedef __attribute__((ext_vector_type(8))) short short8;
typedef __attribute__((ext_vector_type(4))) float f32x4;

__device__ inline unsigned short bf16_rne(float v) {
    union { float f; unsigned u; } c; c.f = v;
    unsigned u = c.u;
    unsigned r = u + 0x7fff + ((u >> 16) & 1);
    return (unsigned short)(r >> 16);
}
__device__ inline float bf16_to_f(unsigned short h) {
    union { unsigned u; float f; } c; c.u = ((unsigned)h) << 16;
    return c.f;
}

// ---------------- phase 1: LDS histograms (row-degree bytes + col buckets) ----------------
__global__ __launch_bounds__(256) void k_hist(const int* __restrict__ ei,
                                              unsigned* __restrict__ histR8,
                                              int* __restrict__ histB) {
    __shared__ unsigned hr[HRW];   // 50 KB: byte-packed per-node row counts
    __shared__ int hb[NB];         // 5 KB: bucket counts
    int b = blockIdx.x, tid = threadIdx.x;
    for (int i = tid; i < HRW; i += 256) hr[i] = 0;
    for (int i = tid; i < NB; i += 256) hb[i] = 0;
    __syncthreads();
    int e0 = b * ECHUNK;
    for (int e = e0 + tid; e < e0 + ECHUNK; e += 256) {
        int r = ei[e];
        int c = ei[EE + e];
        atomicAdd(&hr[r >> 2], 1u << ((r & 3) * 8));  // max ~5 per node per chunk << 255
        atomicAdd(&hb[(unsigned)c / BNODE], 1);
    }
    __syncthreads();
    unsigned* o = histR8 + (size_t)b * HRW;
    for (int i = tid; i < HRW; i += 256) o[i] = hr[i];
    int* ob = histB + (size_t)b * NB;
    for (int i = tid; i < NB; i += 256) ob[i] = hb[i];
}

// ---------------- row-degree reduce -> dinv ----------------
__global__ void k_dinv2(const unsigned* __restrict__ histR8, float* __restrict__ dinv) {
    int i = blockIdx.x * blockDim.x + threadIdx.x;
    if (i >= NN) return;
    int word = i >> 2, sh = (i & 3) * 8;
    int d = 0;
    for (int blk = 0; blk < HB; ++blk)
        d += (histR8[(size_t)blk * HRW + word] >> sh) & 0xFFu;
    float fd = d < 1 ? 1.0f : (float)d;
    dinv[i] = 1.0f / sqrtf(fd);
}

// ---------------- per-bucket prefix across blocks; histB[blk][t] -> prefix; totB = sums ----------------
__global__ void k_colsumB(int* __restrict__ histB, int* __restrict__ totB) {
    int t = blockIdx.x * blockDim.x + threadIdx.x;
    if (t >= NB) return;
    int run = 0;
    for (int blk = 0; blk < HB; ++blk) {
        size_t idx = (size_t)blk * NB + t;
        int v = histB[idx];
        histB[idx] = run;
        run += v;
    }
    totB[t] = run;
}

// ---------------- exclusive scan of 1280 bucket totals -> bptr ----------------
__global__ __launch_bounds__(256) void k_scanT(const int* __restrict__ totB,
                                               int* __restrict__ bptr) {
    __shared__ int wsum[4];
    int tid = threadIdx.x;
    int loc[5], s = 0;
#pragma unroll
    for (int j = 0; j < 5; ++j) { loc[j] = totB[tid * 5 + j]; s += loc[j]; }
    int lane = tid & 63, w = tid >> 6, v = s;
    for (int d = 1; d < 64; d <<= 1) {
        int t = __shfl_up(v, d);
        if (lane >= d) v += t;
    }
    if (lane == 63) wsum[w] = v;
    __syncthreads();
    if (w == 0 && lane < 4) {
        int t = wsum[lane];
        for (int d = 1; d < 4; d <<= 1) {
            int u = __shfl_up(t, d);
            if (lane >= d) t += u;
        }
        wsum[lane] = t;
    }
    __syncthreads();
    int run = (w > 0 ? wsum[w - 1] : 0) + (v - s);
#pragma unroll
    for (int j = 0; j < 5; ++j) { bptr[tid * 5 + j] = run; run += loc[j]; }
    if (tid == 255) bptr[NB] = run;   // == EE
}

// ---------------- phase 2: scatter into buckets via LDS cursors ----------------
__global__ __launch_bounds__(256) void k_scatterB(const int* __restrict__ ei,
                                                  const float* __restrict__ dinv,
                                                  const int* __restrict__ bptr,
                                                  const int* __restrict__ histB,
                                                  int2* __restrict__ ep) {
    __shared__ int cur[NB];
    int b = blockIdx.x, tid = threadIdx.x;
    for (int i = tid; i < NB; i += 256) cur[i] = bptr[i] + histB[(size_t)b * NB + i];
    __syncthreads();
    int e0 = b * ECHUNK;
    for (int e = e0 + tid; e < e0 + ECHUNK; e += 256) {
        int r = ei[e];
        int c = ei[EE + e];
        int bk = (unsigned)c / BNODE;
        int pos = atomicAdd(&cur[bk], 1);
        int2 p;
        p.x = r | ((c - bk * BNODE) << 16);   // row:16b | col_local:6b
        p.y = __float_as_int(dinv[r] * dinv[c]);
        ep[pos] = p;
    }
}

// ---------------- W1 -> bf16 hi/lo split ----------------
__global__ void k_w1split(const float* __restrict__ W1, unsigned short* __restrict__ w1h,
                          unsigned short* __restrict__ w1l) {
    int i = blockIdx.x * blockDim.x + threadIdx.x;
    if (i >= HID * IN_DIM) return;
    float v = W1[i];
    unsigned short h = bf16_rne(v);
    unsigned short l = bf16_rne(v - bf16_to_f(h));
    w1h[i] = h;
    w1l[i] = l;
}

// ---------------- GEMM1 via split-bf16 MFMA: h = relu(BN(x @ W1^T + b1)) ----------------
#define BM 64
#define BK 64
__global__ __launch_bounds__(512) void k_gemm1m(const float* __restrict__ x,
                                                const unsigned short* __restrict__ w1h,
                                                const unsigned short* __restrict__ w1l,
                                                const float* __restrict__ b1,
                                                const float* __restrict__ bnw,
                                                const float* __restrict__ bnb,
                                                const float* __restrict__ bnm,
                                                const float* __restrict__ bnv,
                                                float* __restrict__ h) {
    __shared__ __align__(16) unsigned short Ah[BM * BK];
    __shared__ __align__(16) unsigned short Al[BM * BK];
    __shared__ __align__(16) unsigned short Bh[HID * BK];
    __shared__ __align__(16) unsigned short Bl[HID * BK];
    int tid = threadIdx.x;
    int lane = tid & 63;
    int wid = tid >> 6;
    int wm = wid >> 2;
    int wn = wid & 3;
    int brow = blockIdx.x * BM;

    int ra = tid >> 3, ca = (tid & 7) * 8;
    int rb = tid >> 1, cb = (tid & 1) * 32;

    bool rok = (brow + ra) < NN;
    const float* xa = x + (size_t)(brow + ra) * IN_DIM + ca;
    const unsigned short* bhp = w1h + (size_t)rb * IN_DIM + cb;
    const unsigned short* blp = w1l + (size_t)rb * IN_DIM + cb;

    int abyte = (ra * BK + ca) * 2; abyte ^= (ra & 7) << 4;
    int bbyte0 = (rb * BK + cb) * 2;
    int bsw = (rb & 7) << 4;

    f32x4 acc[2][4];
#pragma unroll
    for (int i = 0; i < 2; ++i)
#pragma unroll
        for (int j = 0; j < 4; ++j) acc[i][j] = (f32x4){0.f, 0.f, 0.f, 0.f};

    int frow_a = wm * 32 + (lane & 15);
    int frow_b = wn * 64 + (lane & 15);
    int fk = (lane >> 4) * 16;

    for (int kt = 0; kt < IN_DIM; kt += BK) {
        float4 v0 = make_float4(0.f, 0.f, 0.f, 0.f), v1 = v0;
        if (rok) {
            v0 = *(const float4*)(xa + kt);
            v1 = *(const float4*)(xa + kt + 4);
        }
        short8 gb_h[4], gb_l[4];
#pragma unroll
        for (int q = 0; q < 4; ++q) {
            gb_h[q] = *(const short8*)(bhp + kt + q * 8);
            gb_l[q] = *(const short8*)(blp + kt + q * 8);
        }
        __syncthreads();
        union { unsigned short u[8]; short8 v; } uh, ul;
        float vv[8] = {v0.x, v0.y, v0.z, v0.w, v1.x, v1.y, v1.z, v1.w};
#pragma unroll
        for (int j = 0; j < 8; ++j) {
            unsigned short hh = bf16_rne(vv[j]);
            uh.u[j] = hh;
            ul.u[j] = bf16_rne(vv[j] - bf16_to_f(hh));
        }
        *(short8*)((char*)Ah + abyte) = uh.v;
        *(short8*)((char*)Al + abyte) = ul.v;
#pragma unroll
        for (int q = 0; q < 4; ++q) {
            int bb = (bbyte0 + q * 16) ^ bsw;
            *(short8*)((char*)Bh + bb) = gb_h[q];
            *(short8*)((char*)Bl + bb) = gb_l[q];
        }
        __syncthreads();

#pragma unroll
        for (int kk = 0; kk < 2; ++kk) {
            short8 afh[2], afl[2];
#pragma unroll
            for (int mi = 0; mi < 2; ++mi) {
                int row = frow_a + mi * 16;
                int byte = (row * BK * 2 + kk * 64 + fk) ^ ((row & 7) << 4);
                afh[mi] = *(short8*)((char*)Ah + byte);
                afl[mi] = *(short8*)((char*)Al + byte);
            }
#pragma unroll
            for (int ni = 0; ni < 4; ++ni) {
                int row = frow_b + ni * 16;
                int byte = (row * BK * 2 + kk * 64 + fk) ^ ((row & 7) << 4);
                short8 bh = *(short8*)((char*)Bh + byte);
                short8 bl = *(short8*)((char*)Bl + byte);
#pragma unroll
                for (int mi = 0; mi < 2; ++mi) {
                    acc[mi][ni] = __builtin_amdgcn_mfma_f32_16x16x32_bf16(afh[mi], bh, acc[mi][ni], 0, 0, 0);
                    acc[mi][ni] = __builtin_amdgcn_mfma_f32_16x16x32_bf16(afl[mi], bh, acc[mi][ni], 0, 0, 0);
                    acc[mi][ni] = __builtin_amdgcn_mfma_f32_16x16x32_bf16(afh[mi], bl, acc[mi][ni], 0, 0, 0);
                }
            }
        }
    }

    int cbase = wn * 64 + (lane & 15);
    float scl[4], off[4];
#pragma unroll
    for (int ni = 0; ni < 4; ++ni) {
        int c = cbase + ni * 16;
        float s = bnw[c] * rsqrtf(bnv[c] + BN_EPS);
        scl[ni] = s;
        off[ni] = (b1[c] - bnm[c]) * s + bnb[c];
    }
#pragma unroll
    for (int mi = 0; mi < 2; ++mi) {
        int r0 = brow + wm * 32 + mi * 16 + ((lane >> 4) << 2);
#pragma unroll
        for (int ni = 0; ni < 4; ++ni) {
            int c = cbase + ni * 16;
#pragma unroll
            for (int j = 0; j < 4; ++j) {
                int r = r0 + j;
                if (r < NN) {
                    float v = acc[mi][ni][j] * scl[ni] + off[ni];
                    h[(size_t)r * HID + c] = v > 0.f ? v : 0.f;
                }
            }
        }
    }
}

// ---------------- GEMM2: z = h @ W2^T + b2; ping = z; out = gamma0 * z ----------------
__global__ __launch_bounds__(256) void k_gemm2(const float* __restrict__ h,
                                               const float* __restrict__ W2,
                                               const float* __restrict__ b2,
                                               const float* __restrict__ gamma,
                                               float* __restrict__ ping,
                                               float* __restrict__ out) {
    __shared__ float W2T[HID * OUT_DIM];
    int tid = threadIdx.x;
    for (int i = tid; i < HID * OUT_DIM; i += 256) {
        int o = i / HID;
        int k = i - o * HID;
        W2T[k * OUT_DIM + o] = W2[i];
    }
    __syncthreads();
    int n = blockIdx.x * 256 + tid;
    if (n >= NN) return;

    float4 acc[10];
#pragma unroll
    for (int o4 = 0; o4 < 10; ++o4) acc[o4] = *(const float4*)&b2[o4 * 4];

    const float4* hr = (const float4*)(h + (size_t)n * HID);
    const float4* wt = (const float4*)W2T;
    for (int j = 0; j < HID / 4; ++j) {
        float4 hv = hr[j];
#pragma unroll
        for (int c = 0; c < 4; ++c) {
            float hk = (c == 0) ? hv.x : (c == 1) ? hv.y : (c == 2) ? hv.z : hv.w;
            const float4* wr = wt + (size_t)(j * 4 + c) * 10;
#pragma unroll
            for (int o4 = 0; o4 < 10; ++o4) {
                float4 w = wr[o4];
                acc[o4].x += hk * w.x;
                acc[o4].y += hk * w.y;
                acc[o4].z += hk * w.z;
                acc[o4].w += hk * w.w;
            }
        }
    }
    float g0 = gamma[0];
    float4* pp = (float4*)(ping + (size_t)n * OUT_DIM);
    float4* op = (float4*)(out + (size_t)n * OUT_DIM);
#pragma unroll
    for (int o4 = 0; o4 < 10; ++o4) {
        pp[o4] = acc[o4];
        float4 g;
        g.x = g0 * acc[o4].x; g.y = g0 * acc[o4].y;
        g.z = g0 * acc[o4].z; g.w = g0 * acc[o4].w;
        op[o4] = g;
    }
}

// ---------------- propagation step: bucket-per-block, LDS accumulate ----------------
__global__ __launch_bounds__(256) void k_spmm2(const int* __restrict__ bptr,
                                               const int2* __restrict__ ep,
                                               const float* __restrict__ cur,
                                               float* __restrict__ nxt,
                                               float* __restrict__ out,
                                               const float* __restrict__ gamma, int k) {
    __shared__ float sacc[BNODE * OUT_DIM];   // 6.4 KB
    int b = blockIdx.x, tid = threadIdx.x;
    for (int i = tid; i < BNODE * OUT_DIM; i += 256) sacc[i] = 0.f;
    __syncthreads();
    int e0 = bptr[b], e1 = bptr[b + 1];
    int lane = tid & 63, wv = tid >> 6;

    int e = e0 + wv;
    for (; e + 4 < e1; e += 8) {
        int2 p0 = ep[e];
        int2 p1 = ep[e + 4];
        int r0 = p0.x & 0xFFFF, c0 = p0.x >> 16;
        int r1 = p1.x & 0xFFFF, c1 = p1.x >> 16;
        float n0 = __int_as_float(p0.y), n1 = __int_as_float(p1.y);
        if (lane < OUT_DIM) {
            float v0 = cur[(size_t)r0 * OUT_DIM + lane];
            float v1 = cur[(size_t)r1 * OUT_DIM + lane];
            atomicAdd(&sacc[c0 * OUT_DIM + lane], n0 * v0);
            atomicAdd(&sacc[c1 * OUT_DIM + lane], n1 * v1);
        }
    }
    for (; e < e1; e += 4) {
        int2 p = ep[e];
        int r = p.x & 0xFFFF, c = p.x >> 16;
        float nm = __int_as_float(p.y);
        if (lane < OUT_DIM)
            atomicAdd(&sacc[c * OUT_DIM + lane], nm * cur[(size_t)r * OUT_DIM + lane]);
    }
    __syncthreads();

    float gk = gamma[k];
    int base = b * BNODE;
    for (int i = tid; i < BNODE * OUT_DIM; i += 256) {
        int node = base + i / OUT_DIM;
        if (node < NN) {
            size_t o = (size_t)node * OUT_DIM + (i % OUT_DIM);
            float v = sacc[i];
            nxt[o] = v;
            out[o] += gk * v;
        }
    }
}

extern "C" void kernel_launch(void* const* d_in, const int* in_sizes, int n_in,
                              void* d_out, int out_size, void* d_ws, size_t ws_size,
                              hipStream_t stream) {
    const float* x   = (const float*)d_in[0];
    const int*   ei  = (const int*)d_in[1];
    const float* W1  = (const float*)d_in[2];
    const float* b1  = (const float*)d_in[3];
    const float* bnw = (const float*)d_in[4];
    const float* bnb = (const float*)d_in[5];
    const float* bnm = (const float*)d_in[6];
    const float* bnv = (const float*)d_in[7];
    const float* W2  = (const float*)d_in[8];
    const float* b2  = (const float*)d_in[9];
    const float* gamma = (const float*)d_in[10];
    float* out = (float*)d_out;

    char* ws = (char*)d_ws;
    const size_t A = 256;
    auto pad = [&](size_t b) { return (b + A - 1) / A * A; };
    size_t off = 0;
    int*   bptr   = (int*)  (ws + off); off += pad((size_t)(NB + 1) * 4);
    int*   totB   = (int*)  (ws + off); off += pad((size_t)NB * 4);
    float* dinv   = (float*)(ws + off); off += pad((size_t)NN * 4);
    int2*  epackB = (int2*) (ws + off); off += pad((size_t)EE * 8);
    float* h      = (float*)(ws + off); off += pad((size_t)NN * HID * 4);
    float* ping   = (float*)(ws + off); off += pad((size_t)NN * OUT_DIM * 4);
    float* pong   = (float*)(ws + off); off += pad((size_t)NN * OUT_DIM * 4);
    unsigned short* w1h = (unsigned short*)(ws + off); off += pad((size_t)HID * IN_DIM * 2);
    unsigned short* w1l = (unsigned short*)(ws + off); off += pad((size_t)HID * IN_DIM * 2);

    // histR8/histB alias h (h written later by gemm1m, after scatterB consumed them)
    unsigned* histR8 = (unsigned*)h;                              // HB*HRW*4 = 12.8 MB
    int* histB = (int*)((char*)h + (size_t)HB * HRW * 4);         // HB*NB*4 = 1.31 MB

    // graph build: LDS histograms -> 2D prefix -> bucketed scatter (no global atomics)
    k_hist<<<HB, 256, 0, stream>>>(ei, histR8, histB);
    k_dinv2<<<(NN + 255) / 256, 256, 0, stream>>>(histR8, dinv);
    k_colsumB<<<(NB + 255) / 256, 256, 0, stream>>>(histB, totB);
    k_scanT<<<1, 256, 0, stream>>>(totB, bptr);
    k_scatterB<<<HB, 256, 0, stream>>>(ei, dinv, bptr, histB, epackB);

    // MLP
    k_w1split<<<(HID * IN_DIM + 255) / 256, 256, 0, stream>>>(W1, w1h, w1l);
    k_gemm1m<<<(NN + BM - 1) / BM, 512, 0, stream>>>(x, w1h, w1l, b1, bnw, bnb, bnm, bnv, h);
    k_gemm2<<<(NN + 255) / 256, 256, 0, stream>>>(h, W2, b2, gamma, ping, out);

    // K propagation steps, ping-pong
    float* cur = ping;
    float* nxt = pong;
    for (int k = 1; k <= KSTEPS; ++k) {
        k_spmm2<<<NB, 256, 0, stream>>>(bptr, epackB, cur, nxt, out, gamma, k);
        float* t = cur; cur = nxt; nxt = t;
    }
}